// Round 9
// baseline (69.848 us; speedup 1.0000x reference)
//
#include <hip/hip_runtime.h>

#define BN 512
#define DIM 128
#define TMARGIN 0.3f
#define NT 512
#define NW 8      // waves per block
#define NBLK 256  // 2 anchors per block

#define FMA4(ACC, U, V)                                                \
    ACC.x += U.x * V.x; ACC.y += U.y * V.y;                            \
    ACC.z += U.z * V.z; ACC.w += U.w * V.w;

__device__ __forceinline__ float hsum4(float4 v) {
    return (v.x + v.y) + (v.z + v.w);
}

// ---------------------------------------------------------------------------
// 256 blocks x 512 threads (1 block/CU). Block b handles anchors b and b+256.
// Phase A: both dist rows in one pass over emb (each row j loaded once).
// Phase B: waves 0-3 scan anchor A, waves 4-7 anchor B.
// Epilogue (single-dispatch, init-free): block b relaxed-stores psum[b], then
// RELEASE-stores pcnt[b] = count+1.0 (>=1.0 always). Block 0 spins on
// acquire loads of pcnt[] until each slot's bit pattern is a float in
// [1.0, 524288.0] — the 0xAA poison pattern (negative), zeros, and NaNs all
// fail, so no memset/ticket is needed. Then block 0 reduces and writes out.
// All 256 blocks are co-resident (1/CU) -> spin cannot deadlock.
// ---------------------------------------------------------------------------
__global__ __launch_bounds__(NT, 1) void triplet_fused_kernel(
        const float* __restrict__ emb,
        const int* __restrict__ labels,
        float* __restrict__ psum,    // [NBLK]
        float* __restrict__ pcnt,    // [NBLK]
        float* __restrict__ out) {
    const int ia   = blockIdx.x;        // anchor A
    const int ib   = blockIdx.x + 256;  // anchor B
    const int tid  = threadIdx.x;
    const int lane = tid & 63;
    const int wave = tid >> 6;

    __shared__ float4 ea4[DIM / 4], eb4[DIM / 4];
    __shared__ float  drowA[BN], drowB[BN];
    __shared__ int    lab[BN];
    __shared__ int    posA[BN], posB[BN];
    __shared__ int    nposA, nposB;
    __shared__ float  wsum[NW];
    __shared__ int    wcnt[NW];

    const float4* emb4 = (const float4*)emb;

    if (tid < 32)      ea4[tid]      = emb4[(size_t)ia * 32 + tid];
    else if (tid < 64) eb4[tid - 32] = emb4[(size_t)ib * 32 + (tid - 32)];
    lab[tid] = labels[tid];
    if (tid == 0) { nposA = 0; nposB = 0; }
    __syncthreads();

    // squared norms of both anchors (per-thread from LDS broadcasts)
    float4 sva = {0,0,0,0}, svb = {0,0,0,0};
#pragma unroll
    for (int q = 0; q < DIM / 4; ++q) {
        float4 ua = ea4[q]; FMA4(sva, ua, ua);
        float4 ub = eb4[q]; FMA4(svb, ub, ub);
    }
    const float sqA = hsum4(sva);
    const float sqB = hsum4(svb);

    // ---------------- Phase A: both dist rows, one pass over emb ----------
    const int rl = lane >> 2;   // row-in-group 0..15
    const int kl = lane & 3;    // k-lane 0..3
#pragma unroll
    for (int c = 0; c < 4; ++c) {
        const int r = c * 128 + wave * 16 + rl;
        float4 da = {0,0,0,0}, db = {0,0,0,0}, qq = {0,0,0,0};
#pragma unroll
        for (int q = 0; q < 8; ++q) {
            const int k4 = kl + 4 * q;
            const float4 v  = emb4[(size_t)r * 32 + k4];
            const float4 ua = ea4[k4];
            const float4 ub = eb4[k4];
            FMA4(da, ua, v);
            FMA4(db, ub, v);
            FMA4(qq, v, v);
        }
        float dotA = hsum4(da), dotB = hsum4(db), sqj = hsum4(qq);
        dotA += __shfl_down(dotA, 1); dotA += __shfl_down(dotA, 2);
        dotB += __shfl_down(dotB, 1); dotB += __shfl_down(dotB, 2);
        sqj  += __shfl_down(sqj, 1);  sqj  += __shfl_down(sqj, 2);
        if (kl == 0) {
            drowA[r] = sqrtf(fmaxf(sqA + sqj - 2.f * dotA, 1e-12f));
            drowB[r] = sqrtf(fmaxf(sqB + sqj - 2.f * dotB, 1e-12f));
        }
    }

    // positives lists (threads 0-255 -> A, 256-511 -> B)
    {
        const int grp  = tid >> 8;          // 0: A, 1: B
        const int t    = tid & 255;
        const int li   = grp ? lab[ib] : lab[ia];
        const int self = grp ? ib : ia;
        int* plist = grp ? posB : posA;
        int* pn    = grp ? &nposB : &nposA;
        for (int j = t; j < BN; j += 256) {
            if (lab[j] == li && j != self) {
                int p = atomicAdd(pn, 1);
                plist[p] = j;
            }
        }
    }
    __syncthreads();

    // ---------------- Phase B: waves 0-3 anchor A, 4-7 anchor B -----------
    const int grp   = wave >> 2;            // 0: A, 1: B
    const int wsub  = wave & 3;
    const float* drow = grp ? drowB : drowA;
    const int*  plist = grp ? posB  : posA;
    const int   npos  = grp ? nposB : nposA;
    const int   li    = grp ? lab[ib] : lab[ia];

    float mn = 1e30f;
    int   hn = 0;
    for (int k = lane; k < BN; k += 64) {
        if (lab[k] != li) { hn = 1; mn = fminf(mn, drow[k]); }
    }
#pragma unroll
    for (int off = 32; off > 0; off >>= 1) {
        mn = fminf(mn, __shfl_down(mn, off));
        hn |= __shfl_down(hn, off);
    }
    mn = __shfl(mn, 0);
    hn = __shfl(hn, 0);

    float lsum = 0.f;
    int   lcnt = 0;
    if (hn) {
        for (int p = wsub; p < npos; p += 4) {
            const float dap = drow[plist[p]];
            const float hi  = dap + TMARGIN;
            float smax = -1e30f;
            for (int k = lane; k < BN; k += 64) {
                const float dan = drow[k];
                if (lab[k] != li && dan > dap && dan < hi)
                    smax = fmaxf(smax, dan);
            }
#pragma unroll
            for (int off = 32; off > 0; off >>= 1)
                smax = fmaxf(smax, __shfl_down(smax, off));
            if (lane == 0) {
                const float dneg = (smax > -1e29f) ? smax : mn;
                lsum += fmaxf(dap - dneg + TMARGIN, 0.f);
                lcnt += 1;
            }
        }
    }
    if (lane == 0) { wsum[wave] = lsum; wcnt[wave] = lcnt; }
    __syncthreads();

    // ---------------- Epilogue: init-free handshake ----------------
    if (tid == 0) {
        float s = 0.f;
        int   c = 0;
#pragma unroll
        for (int w = 0; w < NW; ++w) { s += wsum[w]; c += wcnt[w]; }
        __hip_atomic_store(&psum[blockIdx.x], s, __ATOMIC_RELAXED,
                           __HIP_MEMORY_SCOPE_AGENT);
        // release: orders the psum store before the flag
        __hip_atomic_store(&pcnt[blockIdx.x], (float)c + 1.0f, __ATOMIC_RELEASE,
                           __HIP_MEMORY_SCOPE_AGENT);
    }

    if (blockIdx.x == 0) {
        __syncthreads();  // ensure block 0's own store precedes its poll
        float s = 0.f, c = 0.f;
        if (tid < NBLK) {
            // Spin until slot holds a float in [1.0, 524288.0]. Poison
            // 0xAAAAAAAA, zeros, and NaN bit patterns all fail this test.
            unsigned v;
            for (;;) {
                v = __hip_atomic_load((const unsigned*)&pcnt[tid],
                                      __ATOMIC_ACQUIRE, __HIP_MEMORY_SCOPE_AGENT);
                if (v >= 0x3F800000u && v <= 0x49000000u) break;
                __builtin_amdgcn_s_sleep(1);
            }
            c = __int_as_float((int)v) - 1.0f;
            s = __hip_atomic_load(&psum[tid], __ATOMIC_RELAXED,
                                  __HIP_MEMORY_SCOPE_AGENT);
        }
#pragma unroll
        for (int off = 32; off > 0; off >>= 1) {
            s += __shfl_down(s, off);
            c += __shfl_down(c, off);
        }
        __shared__ float fs[NW], fc[NW];
        if (lane == 0) { fs[wave] = s; fc[wave] = c; }
        __syncthreads();
        if (tid == 0) {
            float total = 0.f, cnt = 0.f;
#pragma unroll
            for (int w = 0; w < 4; ++w) { total += fs[w]; cnt += fc[w]; }
            out[0] = (cnt > 0.f) ? (total / fmaxf(cnt, 1.f)) : 0.f;
        }
    }
}

extern "C" void kernel_launch(void* const* d_in, const int* in_sizes, int n_in,
                              void* d_out, int out_size, void* d_ws, size_t ws_size,
                              hipStream_t stream) {
    const float* emb    = (const float*)d_in[0];
    const int*   labels = (const int*)d_in[1];
    float*       out    = (float*)d_out;
    float*       psum   = (float*)d_ws;   // [256]
    float*       pcnt   = psum + NBLK;    // [256]

    triplet_fused_kernel<<<NBLK, NT, 0, stream>>>(emb, labels, psum, pcnt, out);
}